// Round 1
// baseline (603.181 us; speedup 1.0000x reference)
//
#include <hip/hip_runtime.h>
#include <cmath>

// Problem constants (match reference)
#define B_TOTAL 262144
#define D 16
#define TE 3
#define H 64
#define BLOCK 256

// Stable, fast softplus: max(x,0) + log(1 + exp(-|x|)).
// __expf/__logf map to v_exp_f32/v_log_f32 (trans pipe, overlaps with fmac pipe).
// Abs error ~1e-7 relative to exact; threshold is 2.3e-2 so plenty of margin.
__device__ __forceinline__ float softplus_f(float x) {
    return fmaxf(x, 0.0f) + __logf(1.0f + __expf(-fabsf(x)));
}

__global__ __launch_bounds__(BLOCK) void DiagonalVariance_kernel(
    const float* __restrict__ t,   // [B, TE]
    const float* __restrict__ y,   // [B, D]
    const float* __restrict__ W1,  // [D, 1+TE, H]
    const float* __restrict__ b1,  // [D, H]
    const float* __restrict__ W2,  // [D, H, H]
    const float* __restrict__ b2,  // [D, H]
    const float* __restrict__ W3,  // [D, H, 1]
    const float* __restrict__ b3,  // [D, 1]
    float* __restrict__ out)       // [B, D]
{
    // d is wave-uniform (blockIdx.y) -> all weight loads scalarize to s_load,
    // and fold into v_fmac as SGPR operands (1 SGPR operand per VALU instr is legal).
    const int d = blockIdx.y;
    const int b = blockIdx.x * BLOCK + (int)threadIdx.x;

    // Per-thread input: x = [y[b,d], t[b,0], t[b,1], t[b,2]]
    const float x0 = y[b * D + d];
    const float t0 = t[b * TE + 0];
    const float t1 = t[b * TE + 1];
    const float t2 = t[b * TE + 2];

    const float* __restrict__ W1d = W1 + d * ((1 + TE) * H);
    const float* __restrict__ b1d = b1 + d * H;
    const float* __restrict__ W2d = W2 + d * (H * H);
    const float* __restrict__ b2d = b2 + d * H;

    // h2 accumulators live in registers the whole time (static indexing only).
    float h2[H];
    #pragma unroll
    for (int j = 0; j < H; ++j) h2[j] = b2d[j];

    // Fused layer1 + layer2: for each hidden unit k of layer1, compute h1_k
    // then rank-1 update h2[0..63]. No h1 array -> no dynamic reg indexing.
    // k-loop kept rolled: small code (~75 instrs/iter), I-cache friendly.
    #pragma unroll 1
    for (int k = 0; k < H; ++k) {
        float pre = b1d[k];
        pre = fmaf(x0, W1d[0 * H + k], pre);
        pre = fmaf(t0, W1d[1 * H + k], pre);
        pre = fmaf(t1, W1d[2 * H + k], pre);
        pre = fmaf(t2, W1d[3 * H + k], pre);
        const float h1k = softplus_f(pre);

        const float* __restrict__ w2row = W2d + k * H;  // 64 consecutive floats -> s_load_dwordx16 x4
        #pragma unroll
        for (int j = 0; j < H; ++j) {
            h2[j] = fmaf(h1k, w2row[j], h2[j]);
        }
    }

    // Layer 3: softplus(h2) . W3 + b3, then final softplus.
    const float* __restrict__ W3d = W3 + d * H;
    float acc = b3[d];
    #pragma unroll
    for (int j = 0; j < H; ++j) {
        acc = fmaf(softplus_f(h2[j]), W3d[j], acc);
    }

    out[b * D + d] = softplus_f(acc);
}

extern "C" void kernel_launch(void* const* d_in, const int* in_sizes, int n_in,
                              void* d_out, int out_size, void* d_ws, size_t ws_size,
                              hipStream_t stream) {
    const float* t  = (const float*)d_in[0];
    const float* y  = (const float*)d_in[1];
    const float* W1 = (const float*)d_in[2];
    const float* b1 = (const float*)d_in[3];
    const float* W2 = (const float*)d_in[4];
    const float* b2 = (const float*)d_in[5];
    const float* W3 = (const float*)d_in[6];
    const float* b3 = (const float*)d_in[7];
    float* out = (float*)d_out;

    dim3 grid(B_TOTAL / BLOCK, D);
    DiagonalVariance_kernel<<<grid, dim3(BLOCK), 0, stream>>>(
        t, y, W1, b1, W2, b2, W3, b3, out);
}